// Round 9
// baseline (329.337 us; speedup 1.0000x reference)
//
#include <hip/hip_runtime.h>
#include <math.h>

// FitzHugh-Nagumo RK4. 2047 sequential steps; per-wave time is bounded by
// max(chain_latency*13, issue_cadence*slots) with ONE wave per SIMD.
// R3/R5/R8 all plateau at 148-204 cy/step => single 13-link dependence chain
// is the floor (latency ~10-11 cy/link, single-wave issue ~3.5-4 cy/instr).
// Fix: TWO independent trajectories per thread -> two interleaved chains per
// wave fill each other's latency bubbles. 2048 threads = 32 waves.
// Per-trajectory formulas identical to round 5 (passed, absmax 0.015625).

__global__ __launch_bounds__(64) void fhn_rk4_kernel(
    const float* __restrict__ x0, const float* __restrict__ y0,
    const float* __restrict__ pa, const float* __restrict__ pb,
    const float* __restrict__ pc, float2* __restrict__ out,
    int B, int num_steps)
{
    const int half = B >> 1;
    const int i = blockIdx.x * 64 + threadIdx.x;   // trajectory pair: i, i+half
    if (i >= half) return;

    const float a = pa[0];
    const float b = pb[0];
    const float c = pc[0];

    const float dt  = 0.1f;
    const float h   = 0.05f;
    const float dt6 = 0.1f / 6.0f;
    const float c3  = 1.0f / 3.0f;

    // x-side constants
    const float hc     = h * c;
    const float mhcc3  = -(h * c * c3);
    const float dc     = dt * c;
    const float mdcc3  = -(dt * c * c3);
    const float d6c    = dt6 * c;
    const float md6cc3 = -(dt6 * c * c3);
    const float E4x    = c3 + d6c;

    // y-side constants (f_y linear, coefficients pre-folded)
    const float nic   = -1.0f / c;
    const float nicb  = -b / c;
    const float anc   = a / c;
    const float A1    = 1.0f + h * nicb;
    const float B1    = h * nic;
    const float C1    = h * anc;
    const float hnicb = h * nicb;
    const float dnic  = dt * nic;
    const float dnicb = dt * nicb;
    const float danc  = dt * anc;
    const float d6nic = dt6 * nic;
    const float d6anc = dt6 * anc;
    const float E4y   = c3 + dt6 * nicb;
    const float mc3   = -c3;
    const float c23   = 2.0f * c3;

    // trajectory A: index i;  trajectory B: index i+half
    float xa = x0[i],        ya = y0[i];
    float xb = x0[i + half], yb = y0[i + half];

    float2* oa = out + i;
    float2* ob = out + i + half;
    *oa = make_float2(xa, ya);
    *ob = make_float2(xb, yb);
    oa += B; ob += B;

#pragma unroll 2
    for (int s = 1; s < num_steps; ++s, oa += B, ob += B) {
        // ================= trajectory A =================
        const float ay2 = fmaf(B1, xa, fmaf(A1, ya, C1));
        const float as1 = xa + ya;
        const float ap1 = xa * xa;
        const float aq1 = ap1 * xa;
        const float ax2 = fmaf(mhcc3, aq1, fmaf(hc, as1, xa));

        // ================= trajectory B =================
        const float by2 = fmaf(B1, xb, fmaf(A1, yb, C1));
        const float bs1 = xb + yb;
        const float bp1 = xb * xb;
        const float bq1 = bp1 * xb;
        const float bx2 = fmaf(mhcc3, bq1, fmaf(hc, bs1, xb));

        const float ayha = ya + C1;
        const float ay3 = fmaf(B1, ax2, fmaf(hnicb, ay2, ayha));
        const float as2 = ax2 + ay2;
        const float ap2 = ax2 * ax2;
        const float aq2 = ap2 * ax2;
        const float ax3 = fmaf(mhcc3, aq2, fmaf(hc, as2, xa));

        const float byha = yb + C1;
        const float by3 = fmaf(B1, bx2, fmaf(hnicb, by2, byha));
        const float bs2 = bx2 + by2;
        const float bp2 = bx2 * bx2;
        const float bq2 = bp2 * bx2;
        const float bx3 = fmaf(mhcc3, bq2, fmaf(hc, bs2, xb));

        const float ayda = ya + danc;
        const float ay4 = fmaf(dnic, ax3, fmaf(dnicb, ay3, ayda));
        const float as3 = ax3 + ay3;
        const float ap3 = ax3 * ax3;
        const float aq3 = ap3 * ax3;
        const float ax4 = fmaf(mdcc3, aq3, fmaf(dc, as3, xa));

        const float byda = yb + danc;
        const float by4 = fmaf(dnic, bx3, fmaf(dnicb, by3, byda));
        const float bs3 = bx3 + by3;
        const float bp3 = bx3 * bx3;
        const float bq3 = bp3 * bx3;
        const float bx4 = fmaf(mdcc3, bq3, fmaf(dc, bs3, xb));

        const float ap4 = ax4 * ax4;
        const float aq4 = ap4 * ax4;
        float avx = xa * mc3;
        avx = fmaf(c3, ax2, avx);
        avx = fmaf(c23, ax3, avx);
        avx = fmaf(E4x, ax4, avx);
        avx = fmaf(d6c, ay4, avx);
        xa = fmaf(md6cc3, aq4, avx);
        float awy = fmaf(mc3, ya, d6anc);
        awy = fmaf(c3, ay2, awy);
        awy = fmaf(c23, ay3, awy);
        awy = fmaf(E4y, ay4, awy);
        ya = fmaf(d6nic, ax4, awy);

        const float bp4 = bx4 * bx4;
        const float bq4 = bp4 * bx4;
        float bvx = xb * mc3;
        bvx = fmaf(c3, bx2, bvx);
        bvx = fmaf(c23, bx3, bvx);
        bvx = fmaf(E4x, bx4, bvx);
        bvx = fmaf(d6c, by4, bvx);
        xb = fmaf(md6cc3, bq4, bvx);
        float bwy = fmaf(mc3, yb, d6anc);
        bwy = fmaf(c3, by2, bwy);
        bwy = fmaf(c23, by3, bwy);
        bwy = fmaf(E4y, by4, bwy);
        yb = fmaf(d6nic, bx4, bwy);

        *oa = make_float2(xa, ya);
        *ob = make_float2(xb, yb);
    }
}

extern "C" void kernel_launch(void* const* d_in, const int* in_sizes, int n_in,
                              void* d_out, int out_size, void* d_ws, size_t ws_size,
                              hipStream_t stream) {
    const float* x0 = (const float*)d_in[0];
    const float* y0 = (const float*)d_in[1];
    const float* pa = (const float*)d_in[2];
    const float* pb = (const float*)d_in[3];
    const float* pc = (const float*)d_in[4];
    const int B = in_sizes[0];
    const int num_steps = out_size / (2 * B);

    float2* out = (float2*)d_out;

    const int half = B / 2;
    const int block = 64;
    const int grid = (half + block - 1) / block;
    fhn_rk4_kernel<<<grid, block, 0, stream>>>(x0, y0, pa, pb, pc, out, B, num_steps);
}

// Round 10
// 204.389 us; speedup vs baseline: 1.6113x; 1.6113x over previous
//
#include <hip/hip_runtime.h>
#include <math.h>

// FitzHugh-Nagumo RK4, one thread per trajectory, 2047 sequential steps.
//
// HW model (fit r1-r9): a SOLO wave on a SIMD issues ~1 instruction per 4 cy
// regardless of type (R9: two independent chains per thread gave ZERO overlap
// -> issue-cadence-bound, not latency-bound). v_pk_fma_f32 = 2 f32 ops per
// issue slot -> pk-packed x,y state (R3, 126.5us) is the right structure.
// This round shaves slots: 32-bit byte-offset stores (saddr form: 1 v_add
// per step instead of 64-bit carry pair) + unroll 4 to amortize loop SALU.
// Slot budget ~29/step -> issue floor ~116 cy/step (~99us).
//
// Formulas bit-identical to round 3 (passed, absmax 0.015625):
//   zn = -z/3 + z2/3 + 2/3 z3 + z4/3 + dt6*k4  (exact RK4 identity)

typedef float f2 __attribute__((ext_vector_type(2)));

static __device__ __forceinline__ f2 pkfma(f2 a, f2 b, f2 c) {
    return __builtin_elementwise_fma(a, b, c);
}

__global__ __launch_bounds__(64) void fhn_rk4_kernel(
    const float* __restrict__ x0, const float* __restrict__ y0,
    const float* __restrict__ pa, const float* __restrict__ pb,
    const float* __restrict__ pc, f2* __restrict__ out,
    int B, int num_steps)
{
    const int i = blockIdx.x * 64 + threadIdx.x;
    if (i >= B) return;

    const float a = pa[0];
    const float b = pb[0];
    const float c = pc[0];

    const float dt  = 0.1f;
    const float h   = 0.05f;
    const float dt6 = 0.1f / 6.0f;
    const float c3  = 1.0f / 3.0f;

    const float nic = -1.0f / c;
    const float anc = a / c;
    const float cc3 = c * c3;

    // packed constants (hoisted; live in VGPR pairs across the loop)
    const f2 Cb   = {1.0f, b};                         // sv = {x+y, x+b*y}
    const f2 Ch   = {h * c,  h * nic};                 // half-step linear
    const f2 Cqh  = {-(h * cc3), 0.0f};                // half-step cubic
    const f2 Cd   = {dt * c, dt * nic};                // full-step
    const f2 Cqd  = {-(dt * cc3), 0.0f};
    const f2 C6   = {dt6 * c, dt6 * nic};              // dt/6-scaled (k4 fold)
    const f2 Cq6  = {-(dt6 * cc3), 0.0f};
    const f2 Cha  = {0.0f, h * anc};                   // -a terms, y-half only
    const f2 Cda  = {0.0f, dt * anc};
    const f2 C6a  = {0.0f, dt6 * anc};
    const f2 Cm13 = {-c3, -c3};
    const f2 C13  = {c3, c3};
    const f2 C23  = {2.0f * c3, 2.0f * c3};

    f2 z = {x0[i], y0[i]};

    // 32-bit byte offset from the uniform base -> saddr-form stores,
    // single v_add_u32 per step for the address.
    char* const outc = (char*)out;
    const unsigned strideB = (unsigned)B * 8u;
    unsigned off = (unsigned)i * 8u;

    *(f2*)(outc + off) = z;          // step 0 = initial condition
    off += strideB;

#pragma unroll 4
    for (int s = 1; s < num_steps; ++s, off += strideB) {
        const f2 zbh = z + Cha;               // base for half-steps
        const f2 zbd = z + Cda;               // base for full step

        // ---- stage 1 ----
        const f2 sv1 = pkfma(z.yy, Cb, z.xx);
        const f2 P1  = z * z;
        const f2 Q1  = P1 * z;                // {x^3, y^3} (y^3 unused: *0)
        const f2 z2  = pkfma(Q1, Cqh, pkfma(sv1, Ch, zbh));

        // ---- stage 2 ----
        const f2 sv2 = pkfma(z2.yy, Cb, z2.xx);
        const f2 P2  = z2 * z2;
        const f2 Q2  = P2 * z2;
        const f2 z3  = pkfma(Q2, Cqh, pkfma(sv2, Ch, zbh));

        // ---- stage 3 (full dt) ----
        const f2 sv3 = pkfma(z3.yy, Cb, z3.xx);
        const f2 P3  = z3 * z3;
        const f2 Q3  = P3 * z3;
        const f2 z4  = pkfma(Q3, Cqd, pkfma(sv3, Cd, zbd));

        // ---- combine base:  -z/3 + z2/3 + 2/3 z3 + z4/3 (+ dt6*anc in y) ----
        f2 acc = pkfma(z, Cm13, C6a);
        acc = pkfma(z2, C13, acc);
        acc = pkfma(z3, C23, acc);
        acc = pkfma(z4, C13, acc);

        // ---- stage 4 folded into the final update ----
        const f2 sv4 = pkfma(z4.yy, Cb, z4.xx);
        const f2 P4  = z4 * z4;
        const f2 Q4  = P4 * z4;
        z = pkfma(Q4, Cq6, pkfma(sv4, C6, acc));

        *(f2*)(outc + off) = z;
    }
}

extern "C" void kernel_launch(void* const* d_in, const int* in_sizes, int n_in,
                              void* d_out, int out_size, void* d_ws, size_t ws_size,
                              hipStream_t stream) {
    const float* x0 = (const float*)d_in[0];
    const float* y0 = (const float*)d_in[1];
    const float* pa = (const float*)d_in[2];
    const float* pb = (const float*)d_in[3];
    const float* pc = (const float*)d_in[4];
    const int B = in_sizes[0];
    const int num_steps = out_size / (2 * B);

    f2* out = (f2*)d_out;

    const int block = 64;
    const int grid = (B + block - 1) / block;
    fhn_rk4_kernel<<<grid, block, 0, stream>>>(x0, y0, pa, pb, pc, out, B, num_steps);
}